// Round 1
// baseline (323.045 us; speedup 1.0000x reference)
//
#include <hip/hip_runtime.h>
#include <hip/hip_bf16.h>

// B=4, S=2048, D=1024. q=relu(x Wq^T + bq) etc; out = softmax(q k^T) v.
// R5: replace the 128x128 2-barrier GEMM mainloop with the 256x256 8-phase
// counted-vmcnt schedule (T2+T3+T4+T5 per the technique catalog):
//   - BM=BN=256, BK=64, 512 thr / 8 waves, per-wave 128x64, 32x32x16 MFMA
//   - LDS 128 KiB: A,B each 2 x (256x64 bf16) double-buffered
//   - per iter (2 K-tiles): 4 phases {ds_read frags | stage 1 half-tile |
//     barrier | setprio(1) 16xMFMA setprio(0) | barrier}, vmcnt(4) only at
//     odd-phase ends -> 3 half-tiles stay in flight across barriers
//   - 3-bit XOR chunk swizzle cl = cp ^ (row&7): pre-swizzled GLOBAL source,
//     linear global_load_lds dest, same involution on ds_read_b128
//   - pv: split-K=2 (grid 256 blocks instead of 128) + fp32 atomicAdd into
//     zeroed out (exactly 2 commutative writers per element)
// cvt / transpose_v / softmax unchanged from R4.
//
// ws layout (128 MB):
//   [0,16)   q bf16           [16,32) k bf16
//   [32,48)  v bf16           [48,64) vt bf16
//   [64,128) logits fp32 (softmax overwrites rows in-place with bf16 probs)
//   xb bf16 aliases [64,80), Wb bf16 aliases [80,86) -- consumed by qkv
//   before qk writes logits (stream-ordered). Staging over-reads up to
//   ~2KB past each operand's end on the last K-iter; all stay inside ws
//   (verified per-buffer) and the staged garbage is never consumed.

#define SEQ 2048
#define DIM 1024
#define NB 4
#define MTOT (NB * SEQ)   // 8192

typedef __attribute__((ext_vector_type(8))) short frag_ab;
typedef __attribute__((ext_vector_type(16))) float frag_c16;

__device__ __forceinline__ ushort f2bf(float f) {
    union { float f; unsigned u; } x; x.f = f;
    unsigned r = x.u + 0x7fffu + ((x.u >> 16) & 1u);  // RNE
    return (ushort)(r >> 16);
}

typedef __attribute__((address_space(1))) const unsigned int guint;
typedef __attribute__((address_space(3))) unsigned int luint;

__device__ __forceinline__ void gld_lds16(const void* g, void* l) {
    __builtin_amdgcn_global_load_lds((guint*)g, (luint*)l, 16, 0, 0);
}

__device__ __forceinline__ void bar() {
    asm volatile("" ::: "memory");
    __builtin_amdgcn_s_barrier();
    asm volatile("" ::: "memory");
}

#define VMCNT4 asm volatile("s_waitcnt vmcnt(4)" ::: "memory")

#define TSZ (256 * 64)   // one 256x64 bf16 half-tile in LDS (32 KiB)

// ---------------------------------------------------------------------------
// Stage one 256x64 bf16 half-tile: global (row-major, K-contiguous, ld mult
// of 8) -> LDS, linear dest, source pre-swizzled so logical chunk cl lands
// at physical chunk cp = cl ^ (row&7). 4 x global_load_lds(16B) per thread.
// ---------------------------------------------------------------------------
__device__ __forceinline__ void stage_half(const ushort* __restrict__ P,
                                           size_t ld, int k0, ushort* dst,
                                           int wave, int lane)
{
    const int rin = lane >> 3;       // row within an 8-row chunk
    const int cp  = lane & 7;        // physical 16B chunk slot
    const int cl  = cp ^ rin;        // logical chunk (XOR involution)
    #pragma unroll
    for (int g = 0; g < 4; ++g) {
        int qc  = g * 8 + wave;      // 8-row group id (wave-uniform)
        int row = qc * 8 + rin;      // row&7 == rin
        gld_lds16(P + (size_t)row * ld + k0 + cl * 8, dst + qc * 512);
    }
}

// read one A/B fragment: row, k-step ks (16 wide), lane-half selects 8 elems
__device__ __forceinline__ frag_ab ldfrag(const ushort* S, int row, int ks,
                                          int half)
{
    int pc = (ks * 2 + half) ^ (row & 7);
    return *(const frag_ab*)&S[row * 64 + pc * 8];
}

__device__ __forceinline__ void load_frags(frag_ab (&f)[2][4], const ushort* S,
                                           int r0, int l32, int half)
{
    #pragma unroll
    for (int i = 0; i < 2; ++i)
        #pragma unroll
        for (int ks = 0; ks < 4; ++ks)
            f[i][ks] = ldfrag(S, r0 + i * 32 + l32, ks, half);
}

template<int MP>
__device__ __forceinline__ void mfma_phase(frag_c16 (&acc)[4][2],
                                           const frag_ab (&af)[2][4],
                                           const frag_ab (&bf)[2][4])
{
    __builtin_amdgcn_s_setprio(1);
    #pragma unroll
    for (int ks = 0; ks < 4; ++ks)
        #pragma unroll
        for (int mi = 0; mi < 2; ++mi)
            #pragma unroll
            for (int ni = 0; ni < 2; ++ni)
                acc[MP * 2 + mi][ni] = __builtin_amdgcn_mfma_f32_32x32x16_bf16(
                    af[mi][ks], bf[ni][ks], acc[MP * 2 + mi][ni], 0, 0, 0);
    __builtin_amdgcn_s_setprio(0);
}

// ---------------------------------------------------------------------------
// 256x256-tile 8-phase mainloop. A,B pre-offset to tile row 0, K-contiguous
// (B^T convention). K multiple of 128. Wave w: rows (w>>2)*128, cols (w&3)*64.
// Schedule per iter (K-tiles a=kt even -> buf0, b=kt+1 -> buf1):
//   P0: read B(a),A(a,lo); stage A(b)->As1 | bar | MFMA | bar
//   P1: read A(a,hi);      stage B(a+2)->Bs0 | bar | MFMA | vmcnt(4) bar
//   P2: read B(b),A(b,lo); stage A(a+2)->As0 | bar | MFMA | bar
//   P3: read A(b,hi);      stage B(a+3)->Bs1 | bar | MFMA | vmcnt(4) bar
// vmcnt(4) leaves the newest half-tile (4 loads) in flight; every half a
// phase reads was issued >=2 half-tiles before its vmcnt, and the barrier
// after the vmcnt makes landing global across waves. Buffer writes are only
// issued in the first phase after the buffer's last reader phase's closing
// barrier (reads retire before each wave's MFMA, hence before that barrier).
// Last iter stages garbage K-tiles (in-bounds of ws, never consumed) so the
// vmcnt counts stay uniform.
// ---------------------------------------------------------------------------
__device__ __forceinline__ void gemm256(
    const ushort* __restrict__ A, size_t lda,
    const ushort* __restrict__ B, size_t ldb, int K,
    ushort (&As)[2][TSZ], ushort (&Bs)[2][TSZ], frag_c16 (&acc)[4][2])
{
    const int tid  = threadIdx.x;
    const int wave = tid >> 6;
    const int lane = tid & 63;
    const int l32  = lane & 31;
    const int half = lane >> 5;
    const int wm   = (wave >> 2) * 128;
    const int wn   = (wave & 3) * 64;

    stage_half(B, ldb, 0,  Bs[0], wave, lane);
    stage_half(A, lda, 0,  As[0], wave, lane);
    stage_half(B, ldb, 64, Bs[1], wave, lane);
    VMCNT4;
    __builtin_amdgcn_s_barrier();
    asm volatile("" ::: "memory");

    const int nkt = K >> 6;
    for (int kt = 0; kt < nkt; kt += 2) {
        frag_ab bfe[2][4], bfo[2][4], af[2][4];
        // ---- P0: (kt, rows lo) from buf0
        load_frags(bfe, Bs[0], wn, l32, half);
        load_frags(af,  As[0], wm, l32, half);
        stage_half(A, lda, (kt + 1) * 64, As[1], wave, lane);
        bar();
        mfma_phase<0>(acc, af, bfe);
        bar();
        // ---- P1: (kt, rows hi)
        load_frags(af, As[0], wm + 64, l32, half);
        stage_half(B, ldb, (kt + 2) * 64, Bs[0], wave, lane);
        bar();
        mfma_phase<1>(acc, af, bfe);
        VMCNT4;
        bar();
        // ---- P2: (kt+1, rows lo) from buf1
        load_frags(bfo, Bs[1], wn, l32, half);
        load_frags(af,  As[1], wm, l32, half);
        stage_half(A, lda, (kt + 2) * 64, As[0], wave, lane);
        bar();
        mfma_phase<0>(acc, af, bfo);
        bar();
        // ---- P3: (kt+1, rows hi)
        load_frags(af, As[1], wm + 64, l32, half);
        stage_half(B, ldb, (kt + 3) * 64, Bs[1], wave, lane);
        bar();
        mfma_phase<1>(acc, af, bfo);
        VMCNT4;
        bar();
    }
}

// C/D layout (32x32): col = lane&31, row = (reg&3) + 8*(reg>>2) + 4*(lane>>5)

// ---------------------------------------------------------------------------
// fp32 -> bf16 converter, x + 3 weights in one launch (memory-bound)
// ---------------------------------------------------------------------------
#define NX4 (MTOT * DIM / 4)          // 2M float4 for x
#define NW4 (DIM * DIM / 4)           // 256K float4 per W
__global__ __launch_bounds__(256) void cvt_kernel(
    const float* __restrict__ x,
    const float* __restrict__ Wq, const float* __restrict__ Wk,
    const float* __restrict__ Wv,
    ushort* __restrict__ xb, ushort* __restrict__ Wb)
{
    size_t i = (size_t)blockIdx.x * 256 + threadIdx.x;
    const float* src; ushort* dst; size_t idx;
    if (i < NX4) { src = x; dst = xb; idx = i; }
    else {
        size_t j = i - NX4;
        int w = (int)(j >> 18);               // j / NW4
        idx = j & (NW4 - 1);
        src = w == 0 ? Wq : (w == 1 ? Wk : Wv);
        dst = Wb + (size_t)w * DIM * DIM;
    }
    float4 f = ((const float4*)src)[idx];
    ushort4 u; u.x = f2bf(f.x); u.y = f2bf(f.y); u.z = f2bf(f.z); u.w = f2bf(f.w);
    ((ushort4*)dst)[idx] = u;
}

// ---------------------------------------------------------------------------
// Kernel 1: q/k/v = relu(x W^T + b) -> bf16.  grid (32, 4, 3), block 512
// ---------------------------------------------------------------------------
__global__ __launch_bounds__(512, 2) void qkv_kernel(
    const ushort* __restrict__ xb, const ushort* __restrict__ Wb,
    const float* __restrict__ bq, const float* __restrict__ bk,
    const float* __restrict__ bv,
    ushort* __restrict__ q, ushort* __restrict__ kk, ushort* __restrict__ v)
{
    __shared__ ushort As[2][TSZ];
    __shared__ ushort Bs[2][TSZ];

    const float* bias; ushort* out;
    if (blockIdx.z == 0)      { bias = bq; out = q; }
    else if (blockIdx.z == 1) { bias = bk; out = kk; }
    else                      { bias = bv; out = v; }
    const ushort* W = Wb + (size_t)blockIdx.z * DIM * DIM;

    const int m0 = blockIdx.x * 256;
    const int n0 = blockIdx.y * 256;

    frag_c16 acc[4][2] = {};
    gemm256(xb + (size_t)m0 * DIM, DIM, W + (size_t)n0 * DIM, DIM, DIM,
            As, Bs, acc);

    const int tid  = threadIdx.x;
    const int wave = tid >> 6;
    const int lane = tid & 63;
    const int l32  = lane & 31;
    const int half = lane >> 5;
    const int wm   = (wave >> 2) * 128;
    const int wn   = (wave & 3) * 64;

    #pragma unroll
    for (int ni = 0; ni < 2; ++ni) {
        int col = n0 + wn + ni * 32 + l32;
        float bb = bias[col];
        #pragma unroll
        for (int mi = 0; mi < 4; ++mi)
            #pragma unroll
            for (int r = 0; r < 16; ++r) {
                int row = m0 + wm + mi * 32 + (r & 3) + 8 * (r >> 2) + 4 * half;
                float val = acc[mi][ni][r] + bb;
                val = val > 0.0f ? val : 0.0f;
                out[(size_t)row * DIM + col] = f2bf(val);
            }
    }
}

// ---------------------------------------------------------------------------
// Kernel 2: vt[bz][o][s] = v[bz][s][o]  (bf16 64x64 LDS transpose)
// ---------------------------------------------------------------------------
__global__ __launch_bounds__(256) void transpose_v(
    const ushort* __restrict__ v, ushort* __restrict__ vt)
{
    __shared__ ushort T[64][72];
    const int bz = blockIdx.z;
    const int s0 = blockIdx.x * 64;
    const int o0 = blockIdx.y * 64;
    const int t  = threadIdx.x;

    #pragma unroll
    for (int p = 0; p < 4; ++p) {
        int sl = p * 16 + (t >> 4);
        int o4 = (t & 15) * 4;
        ushort4 u = *(const ushort4*)&v[(size_t)(bz * SEQ + s0 + sl) * DIM + o0 + o4];
        *(ushort4*)&T[sl][o4] = u;
    }
    __syncthreads();
    #pragma unroll
    for (int p = 0; p < 4; ++p) {
        int ol = p * 16 + (t >> 4);
        int s4 = (t & 15) * 4;
        ushort4 u;
        u.x = T[s4 + 0][ol]; u.y = T[s4 + 1][ol];
        u.z = T[s4 + 2][ol]; u.w = T[s4 + 3][ol];
        *(ushort4*)&vt[(size_t)(bz * DIM + o0 + ol) * SEQ + s0 + s4] = u;
    }
}

// ---------------------------------------------------------------------------
// Kernel 3: logits = q k^T (fp32).  grid (8,8,4), block 512
// ---------------------------------------------------------------------------
__global__ __launch_bounds__(512, 2) void qk_kernel(
    const ushort* __restrict__ q, const ushort* __restrict__ kk,
    float* __restrict__ logits)
{
    __shared__ ushort As[2][TSZ];
    __shared__ ushort Bs[2][TSZ];

    const int bz = blockIdx.z;
    const int m0 = blockIdx.x * 256;
    const int n0 = blockIdx.y * 256;
    const size_t base = (size_t)bz * SEQ;

    frag_c16 acc[4][2] = {};
    gemm256(q + (base + m0) * DIM, DIM, kk + (base + n0) * DIM, DIM, DIM,
            As, Bs, acc);

    const int tid  = threadIdx.x;
    const int wave = tid >> 6;
    const int lane = tid & 63;
    const int l32  = lane & 31;
    const int half = lane >> 5;
    const int wm   = (wave >> 2) * 128;
    const int wn   = (wave & 3) * 64;

    #pragma unroll
    for (int mi = 0; mi < 4; ++mi)
        #pragma unroll
        for (int r = 0; r < 16; ++r) {
            int row = m0 + wm + mi * 32 + (r & 3) + 8 * (r >> 2) + 4 * half;
            #pragma unroll
            for (int ni = 0; ni < 2; ++ni) {
                int col = n0 + wn + ni * 32 + l32;
                logits[(base + row) * SEQ + col] = acc[mi][ni][r];
            }
        }
}

// ---------------------------------------------------------------------------
// Kernel 4: row softmax over 2048 fp32, write bf16 probs in-place.
// ---------------------------------------------------------------------------
__global__ __launch_bounds__(256) void softmax_kernel(float* __restrict__ logits)
{
    float* p = logits + (size_t)blockIdx.x * SEQ;
    const int t = threadIdx.x;
    const int wave = t >> 6, lane = t & 63;

    float4 a = ((const float4*)p)[t];
    float4 b = ((const float4*)p)[t + 256];

    float m = fmaxf(fmaxf(fmaxf(a.x, a.y), fmaxf(a.z, a.w)),
                    fmaxf(fmaxf(b.x, b.y), fmaxf(b.z, b.w)));
    #pragma unroll
    for (int off = 32; off; off >>= 1) m = fmaxf(m, __shfl_down(m, off, 64));

    __shared__ float red[4];
    if (lane == 0) red[wave] = m;
    __syncthreads();
    m = fmaxf(fmaxf(red[0], red[1]), fmaxf(red[2], red[3]));

    a.x = __expf(a.x - m); a.y = __expf(a.y - m);
    a.z = __expf(a.z - m); a.w = __expf(a.w - m);
    b.x = __expf(b.x - m); b.y = __expf(b.y - m);
    b.z = __expf(b.z - m); b.w = __expf(b.w - m);

    float s = (a.x + a.y + a.z + a.w) + (b.x + b.y + b.z + b.w);
    #pragma unroll
    for (int off = 32; off; off >>= 1) s += __shfl_down(s, off, 64);
    __syncthreads();
    if (lane == 0) red[wave] = s;
    __syncthreads();
    s = red[0] + red[1] + red[2] + red[3];
    float inv = 1.0f / s;

    ushort* o = (ushort*)p;
    ushort4 u0, u1;
    u0.x = f2bf(a.x * inv); u0.y = f2bf(a.y * inv);
    u0.z = f2bf(a.z * inv); u0.w = f2bf(a.w * inv);
    u1.x = f2bf(b.x * inv); u1.y = f2bf(b.y * inv);
    u1.z = f2bf(b.z * inv); u1.w = f2bf(b.w * inv);
    ((ushort4*)o)[t]       = u0;
    ((ushort4*)o)[t + 256] = u1;
}

// ---------------------------------------------------------------------------
// Kernel 5: out += P vt^T (fp32), split-K=2 via atomics. P rows stride 4096
// ushorts. grid (8,4,8): z = bz*2 + khalf. out must be pre-zeroed.
// ---------------------------------------------------------------------------
__global__ __launch_bounds__(512, 2) void pv_kernel(
    const ushort* __restrict__ probs, const ushort* __restrict__ vt,
    float* __restrict__ out)
{
    __shared__ ushort As[2][TSZ];
    __shared__ ushort Bs[2][TSZ];

    const int bz = blockIdx.z >> 1;
    const int kh = blockIdx.z & 1;
    const int m0 = blockIdx.x * 256;
    const int n0 = blockIdx.y * 256;

    frag_c16 acc[4][2] = {};
    gemm256(probs + ((size_t)(bz * SEQ + m0)) * 4096 + kh * 1024, 4096,
            vt + ((size_t)(bz * DIM + n0)) * SEQ + kh * 1024, SEQ, 1024,
            As, Bs, acc);

    const int tid  = threadIdx.x;
    const int wave = tid >> 6;
    const int lane = tid & 63;
    const int l32  = lane & 31;
    const int half = lane >> 5;
    const int wm   = (wave >> 2) * 128;
    const int wn   = (wave & 3) * 64;

    #pragma unroll
    for (int mi = 0; mi < 4; ++mi)
        #pragma unroll
        for (int r = 0; r < 16; ++r) {
            int row = m0 + wm + mi * 32 + (r & 3) + 8 * (r >> 2) + 4 * half;
            #pragma unroll
            for (int ni = 0; ni < 2; ++ni) {
                int col = n0 + wn + ni * 32 + l32;
                atomicAdd(&out[((size_t)(bz * SEQ + row)) * DIM + col],
                          acc[mi][ni][r]);
            }
        }
}

// ---------------------------------------------------------------------------
extern "C" void kernel_launch(void* const* d_in, const int* in_sizes, int n_in,
                              void* d_out, int out_size, void* d_ws, size_t ws_size,
                              hipStream_t stream)
{
    const float* x  = (const float*)d_in[0];
    const float* Wq = (const float*)d_in[1];
    const float* bq = (const float*)d_in[2];
    const float* Wk = (const float*)d_in[3];
    const float* bk = (const float*)d_in[4];
    const float* Wv = (const float*)d_in[5];
    const float* bv = (const float*)d_in[6];
    float* out = (float*)d_out;

    char* ws = (char*)d_ws;
    ushort* q      = (ushort*)(ws);                           // 16 MB
    ushort* kk     = (ushort*)(ws + ((size_t)16 << 20));      // 16 MB
    ushort* v      = (ushort*)(ws + ((size_t)32 << 20));      // 16 MB
    ushort* vt     = (ushort*)(ws + ((size_t)48 << 20));      // 16 MB
    float*  logits = (float*) (ws + ((size_t)64 << 20));      // 64 MB
    ushort* xb     = (ushort*)(ws + ((size_t)64 << 20));      // aliases logits
    ushort* Wb     = (ushort*)(ws + ((size_t)80 << 20));      // aliases logits

    // zero out for pv's split-K atomics (runs before anything touches out)
    hipMemsetAsync(out, 0, (size_t)MTOT * DIM * sizeof(float), stream);

    cvt_kernel<<<dim3((NX4 + 3 * NW4) / 256), 256, 0, stream>>>(
        x, Wq, Wk, Wv, xb, Wb);

    qkv_kernel<<<dim3(MTOT / 256, DIM / 256, 3), 512, 0, stream>>>(
        xb, Wb, bq, bk, bv, q, kk, v);
    transpose_v<<<dim3(SEQ / 64, DIM / 64, NB), 256, 0, stream>>>(v, vt);
    qk_kernel<<<dim3(SEQ / 256, SEQ / 256, NB), 512, 0, stream>>>(q, kk, logits);
    softmax_kernel<<<NB * SEQ, 256, 0, stream>>>(logits);
    pv_kernel<<<dim3(SEQ / 256, DIM / 256, NB * 2), 512, 0, stream>>>(
        (const ushort*)logits, vt, out);
}

// Round 2
// 265.305 us; speedup vs baseline: 1.2176x; 1.2176x over previous
//
#include <hip/hip_runtime.h>
#include <hip/hip_bf16.h>

// B=4, S=2048, D=1024. q=relu(x Wq^T + bq) etc; out = softmax(q k^T) v.
// R6: revert R5's 8-phase/atomic experiment (pv atomics cost ~30us; 8-phase
// core measured == 128^2 core). Keep the proven single-buffered 128^2
// mainloop (R4, 746 TF) with three targeted fixes:
//   1. BK=64 + full 3-bit XOR chunk swizzle cl = cp ^ (row&7). R4's 2-bit
//      swizzle measured 16 extra cy per ds_read_b128 (6.29M/393K); R5's
//      3-bit variant measured 4. Same MFMA k-order -> identical numerics.
//   2. transpose_v fused into qkv's z==2 epilogue: C-layout r&3 -> 4
//      consecutive s-rows -> ushort4 stores directly into vt. Kills the
//      transpose kernel + 32 MB of traffic.
//   3. softmax: 1 wave per row, shfl_xor reduce, no LDS/barriers.
//
// ws layout (128 MB):
//   [0,16)   q bf16           [16,32) k bf16
//   [32,48)  (unused)         [48,64) vt bf16 (written by qkv z==2)
//   [64,128) logits fp32 (softmax overwrites rows in-place with bf16 probs)
//   xb bf16 aliases [64,80), Wb bf16 aliases [80,86) -- consumed by qkv
//   before qk writes logits (stream-ordered).

#define SEQ 2048
#define DIM 1024
#define NB 4
#define MTOT (NB * SEQ)   // 8192

typedef __attribute__((ext_vector_type(8))) short frag_ab;
typedef __attribute__((ext_vector_type(16))) float frag_c16;

__device__ __forceinline__ ushort f2bf(float f) {
    union { float f; unsigned u; } x; x.f = f;
    unsigned r = x.u + 0x7fffu + ((x.u >> 16) & 1u);  // RNE
    return (ushort)(r >> 16);
}

typedef __attribute__((address_space(1))) const unsigned int guint;
typedef __attribute__((address_space(3))) unsigned int luint;

__device__ __forceinline__ void gld_lds16(const void* g, void* l) {
    __builtin_amdgcn_global_load_lds((guint*)g, (luint*)l, 16, 0, 0);
}

// ---------------------------------------------------------------------------
// 128x128-tile bf16 MFMA mainloop, 32x32x16 shape, BK=64, single-buffered.
// A,B pre-offset to tile row 0, K-contiguous (B^T convention), lda/ldb
// multiples of 8, K multiple of 64.
// LDS tiles 128x64 unpadded. Staging: per wave, 64 lanes cover 8 rows x 8
// 16B-chunks; logical chunk cl = cp ^ rin so logical chunk cl of row r lands
// at physical chunk cl ^ (r&7) (global source pre-swizzled, LDS dest linear).
// Read side applies the same involution: pc = (ks*2+half) ^ (row&7) ->
// within each 16-lane group every bank is hit by exactly 2 lanes (free).
// Wave w owns the 64x64 subtile (wm,wn), split 2x2 into 32x32 MFMA tiles.
// ---------------------------------------------------------------------------
__device__ __forceinline__ void gemm_tiles(
    const ushort* __restrict__ A, size_t lda,
    const ushort* __restrict__ B, size_t ldb, int K,
    ushort* As, ushort* Bs, frag_c16 (&acc)[2][2])
{
    const int tid  = threadIdx.x;
    const int wave = tid >> 6;
    const int lane = tid & 63;
    const int l32  = lane & 31;
    const int half = lane >> 5;
    const int rin  = lane >> 3;      // row within an 8-row group
    const int cp   = lane & 7;       // physical 16B chunk slot
    const int cl   = cp ^ rin;       // logical chunk (XOR involution)
    const int wm = (wave & 1) * 64;
    const int wn = (wave >> 1) * 64;

    for (int k0 = 0; k0 < K; k0 += 64) {
        #pragma unroll
        for (int g = 0; g < 4; ++g) {
            int qc  = g * 4 + wave;      // 8-row group id (wave-uniform)
            int row = qc * 8 + rin;      // row&7 == rin
            gld_lds16(A + (size_t)row * lda + k0 + cl * 8, As + qc * 512);
            gld_lds16(B + (size_t)row * ldb + k0 + cl * 8, Bs + qc * 512);
        }
        __syncthreads();
        frag_ab af[2][4], bf[2][4];
        #pragma unroll
        for (int mi = 0; mi < 2; ++mi) {
            int row = wm + mi * 32 + l32;
            int sw = row & 7;
            #pragma unroll
            for (int ks = 0; ks < 4; ++ks) {
                int c = (ks * 2 + half) ^ sw;
                af[mi][ks] = *(const frag_ab*)&As[row * 64 + c * 8];
            }
        }
        #pragma unroll
        for (int ni = 0; ni < 2; ++ni) {
            int row = wn + ni * 32 + l32;
            int sw = row & 7;
            #pragma unroll
            for (int ks = 0; ks < 4; ++ks) {
                int c = (ks * 2 + half) ^ sw;
                bf[ni][ks] = *(const frag_ab*)&Bs[row * 64 + c * 8];
            }
        }
        #pragma unroll
        for (int ks = 0; ks < 4; ++ks)
            #pragma unroll
            for (int mi = 0; mi < 2; ++mi)
                #pragma unroll
                for (int ni = 0; ni < 2; ++ni)
                    acc[mi][ni] = __builtin_amdgcn_mfma_f32_32x32x16_bf16(
                        af[mi][ks], bf[ni][ks], acc[mi][ni], 0, 0, 0);
        __syncthreads();
    }
}

// C/D layout (32x32): col = lane&31, row = (reg&3) + 8*(reg>>2) + 4*(lane>>5)

// ---------------------------------------------------------------------------
// fp32 -> bf16 converter, x + 3 weights in one launch (memory-bound)
// ---------------------------------------------------------------------------
#define NX4 (MTOT * DIM / 4)          // 2M float4 for x
#define NW4 (DIM * DIM / 4)           // 256K float4 per W
__global__ __launch_bounds__(256) void cvt_kernel(
    const float* __restrict__ x,
    const float* __restrict__ Wq, const float* __restrict__ Wk,
    const float* __restrict__ Wv,
    ushort* __restrict__ xb, ushort* __restrict__ Wb)
{
    size_t i = (size_t)blockIdx.x * 256 + threadIdx.x;
    const float* src; ushort* dst; size_t idx;
    if (i < NX4) { src = x; dst = xb; idx = i; }
    else {
        size_t j = i - NX4;
        int w = (int)(j >> 18);               // j / NW4
        idx = j & (NW4 - 1);
        src = w == 0 ? Wq : (w == 1 ? Wk : Wv);
        dst = Wb + (size_t)w * DIM * DIM;
    }
    float4 f = ((const float4*)src)[idx];
    ushort4 u; u.x = f2bf(f.x); u.y = f2bf(f.y); u.z = f2bf(f.z); u.w = f2bf(f.w);
    ((ushort4*)dst)[idx] = u;
}

// ---------------------------------------------------------------------------
// Kernel 1: q/k/v = relu(x W^T + b) -> bf16.  grid (64, 8, 3), block 256.
// z==0 -> q row-major, z==1 -> k row-major, z==2 -> V written TRANSPOSED
// into vt[bz][o][s] (r&3 packs 4 consecutive s -> ushort4 stores).
// ---------------------------------------------------------------------------
__global__ __launch_bounds__(256) void qkv_kernel(
    const ushort* __restrict__ xb, const ushort* __restrict__ Wb,
    const float* __restrict__ bq, const float* __restrict__ bk,
    const float* __restrict__ bv,
    ushort* __restrict__ q, ushort* __restrict__ kk, ushort* __restrict__ vt)
{
    const float* bias;
    if (blockIdx.z == 0)      bias = bq;
    else if (blockIdx.z == 1) bias = bk;
    else                      bias = bv;
    const ushort* W = Wb + (size_t)blockIdx.z * DIM * DIM;

    __shared__ ushort As[128 * 64];
    __shared__ ushort Bs[128 * 64];

    const int tid  = threadIdx.x;
    const int wave = tid >> 6;
    const int lane = tid & 63;
    const int l32  = lane & 31;
    const int half = lane >> 5;
    const int m0 = blockIdx.x * 128;
    const int n0 = blockIdx.y * 128;
    const int wm = (wave & 1) * 64;
    const int wn = (wave >> 1) * 64;

    frag_c16 acc[2][2] = {};
    gemm_tiles(xb + (size_t)m0 * DIM, DIM, W + (size_t)n0 * DIM, DIM, DIM,
               As, Bs, acc);

    if (blockIdx.z == 2) {
        // vt[bz][col][s]; tile rows never straddle a batch (128 | 2048)
        const int bz = m0 >> 11;
        const int sb = (m0 & (SEQ - 1)) + wm;
        #pragma unroll
        for (int ni = 0; ni < 2; ++ni) {
            int col = n0 + wn + ni * 32 + l32;
            float bb = bias[col];
            ushort* vrow = vt + ((size_t)(bz * DIM + col)) * SEQ;
            #pragma unroll
            for (int mi = 0; mi < 2; ++mi)
                #pragma unroll
                for (int g = 0; g < 4; ++g) {
                    int s0 = sb + mi * 32 + 8 * g + 4 * half;
                    ushort4 u;
                    #pragma unroll
                    for (int j = 0; j < 4; ++j) {
                        float val = acc[mi][ni][4 * g + j] + bb;
                        val = val > 0.0f ? val : 0.0f;
                        ((ushort*)&u)[j] = f2bf(val);
                    }
                    *(ushort4*)&vrow[s0] = u;
                }
        }
    } else {
        ushort* out = blockIdx.z == 0 ? q : kk;
        #pragma unroll
        for (int ni = 0; ni < 2; ++ni) {
            int col = n0 + wn + ni * 32 + l32;
            float bb = bias[col];
            #pragma unroll
            for (int mi = 0; mi < 2; ++mi)
                #pragma unroll
                for (int r = 0; r < 16; ++r) {
                    int row = m0 + wm + mi * 32 + (r & 3) + 8 * (r >> 2) + 4 * half;
                    float val = acc[mi][ni][r] + bb;
                    val = val > 0.0f ? val : 0.0f;
                    out[(size_t)row * DIM + col] = f2bf(val);
                }
        }
    }
}

// ---------------------------------------------------------------------------
// Kernel 3: logits = q k^T (fp32).  grid (16,16,4)
// ---------------------------------------------------------------------------
__global__ __launch_bounds__(256) void qk_kernel(
    const ushort* __restrict__ q, const ushort* __restrict__ kk,
    float* __restrict__ logits)
{
    __shared__ ushort As[128 * 64];
    __shared__ ushort Bs[128 * 64];

    const int tid  = threadIdx.x;
    const int wave = tid >> 6;
    const int lane = tid & 63;
    const int l32  = lane & 31;
    const int half = lane >> 5;
    const int bz = blockIdx.z;
    const int m0 = blockIdx.x * 128;
    const int n0 = blockIdx.y * 128;
    const int wm = (wave & 1) * 64;
    const int wn = (wave >> 1) * 64;
    const size_t base = (size_t)bz * SEQ;

    frag_c16 acc[2][2] = {};
    gemm_tiles(q + (base + m0) * DIM, DIM, kk + (base + n0) * DIM, DIM, DIM,
               As, Bs, acc);

    #pragma unroll
    for (int mi = 0; mi < 2; ++mi)
        #pragma unroll
        for (int r = 0; r < 16; ++r) {
            int row = m0 + wm + mi * 32 + (r & 3) + 8 * (r >> 2) + 4 * half;
            #pragma unroll
            for (int ni = 0; ni < 2; ++ni) {
                int col = n0 + wn + ni * 32 + l32;
                logits[(base + row) * SEQ + col] = acc[mi][ni][r];
            }
        }
}

// ---------------------------------------------------------------------------
// Kernel 4: row softmax over 2048 fp32, write bf16 probs in-place.
// 1 wave per row, 4 rows per block, no LDS / no barriers.
// ---------------------------------------------------------------------------
__global__ __launch_bounds__(256) void softmax_kernel(float* __restrict__ logits)
{
    const int row  = blockIdx.x * 4 + (threadIdx.x >> 6);
    const int lane = threadIdx.x & 63;
    float* p = logits + (size_t)row * SEQ;

    float4 x[8];
    #pragma unroll
    for (int i = 0; i < 8; ++i) x[i] = ((const float4*)p)[lane + 64 * i];

    float m = -3.4e38f;
    #pragma unroll
    for (int i = 0; i < 8; ++i)
        m = fmaxf(m, fmaxf(fmaxf(x[i].x, x[i].y), fmaxf(x[i].z, x[i].w)));
    #pragma unroll
    for (int off = 32; off; off >>= 1) m = fmaxf(m, __shfl_xor(m, off, 64));

    float s = 0.0f;
    #pragma unroll
    for (int i = 0; i < 8; ++i) {
        x[i].x = __expf(x[i].x - m); x[i].y = __expf(x[i].y - m);
        x[i].z = __expf(x[i].z - m); x[i].w = __expf(x[i].w - m);
        s += (x[i].x + x[i].y) + (x[i].z + x[i].w);
    }
    #pragma unroll
    for (int off = 32; off; off >>= 1) s += __shfl_xor(s, off, 64);
    float inv = 1.0f / s;

    ushort* o = (ushort*)p;
    #pragma unroll
    for (int i = 0; i < 8; ++i) {
        ushort4 u;
        u.x = f2bf(x[i].x * inv); u.y = f2bf(x[i].y * inv);
        u.z = f2bf(x[i].z * inv); u.w = f2bf(x[i].w * inv);
        ((ushort4*)o)[lane + 64 * i] = u;
    }
}

// ---------------------------------------------------------------------------
// Kernel 5: out = P vt^T (fp32). P rows stride 4096 ushorts. grid (16,8,4)
// ---------------------------------------------------------------------------
__global__ __launch_bounds__(256) void pv_kernel(
    const ushort* __restrict__ probs, const ushort* __restrict__ vt,
    float* __restrict__ out)
{
    __shared__ ushort As[128 * 64];
    __shared__ ushort Bs[128 * 64];

    const int tid  = threadIdx.x;
    const int wave = tid >> 6;
    const int lane = tid & 63;
    const int l32  = lane & 31;
    const int half = lane >> 5;
    const int bz = blockIdx.z;
    const int m0 = blockIdx.x * 128;
    const int n0 = blockIdx.y * 128;
    const int wm = (wave & 1) * 64;
    const int wn = (wave >> 1) * 64;

    frag_c16 acc[2][2] = {};
    gemm_tiles(probs + ((size_t)(bz * SEQ + m0)) * 4096, 4096,
               vt + ((size_t)(bz * DIM + n0)) * SEQ, SEQ, SEQ,
               As, Bs, acc);

    #pragma unroll
    for (int mi = 0; mi < 2; ++mi)
        #pragma unroll
        for (int r = 0; r < 16; ++r) {
            int row = m0 + wm + mi * 32 + (r & 3) + 8 * (r >> 2) + 4 * half;
            #pragma unroll
            for (int ni = 0; ni < 2; ++ni) {
                int col = n0 + wn + ni * 32 + l32;
                out[((size_t)(bz * SEQ + row)) * DIM + col] = acc[mi][ni][r];
            }
        }
}

// ---------------------------------------------------------------------------
extern "C" void kernel_launch(void* const* d_in, const int* in_sizes, int n_in,
                              void* d_out, int out_size, void* d_ws, size_t ws_size,
                              hipStream_t stream)
{
    const float* x  = (const float*)d_in[0];
    const float* Wq = (const float*)d_in[1];
    const float* bq = (const float*)d_in[2];
    const float* Wk = (const float*)d_in[3];
    const float* bk = (const float*)d_in[4];
    const float* Wv = (const float*)d_in[5];
    const float* bv = (const float*)d_in[6];
    float* out = (float*)d_out;

    char* ws = (char*)d_ws;
    ushort* q      = (ushort*)(ws);                           // 16 MB
    ushort* kk     = (ushort*)(ws + ((size_t)16 << 20));      // 16 MB
    ushort* vt     = (ushort*)(ws + ((size_t)48 << 20));      // 16 MB
    float*  logits = (float*) (ws + ((size_t)64 << 20));      // 64 MB
    ushort* xb     = (ushort*)(ws + ((size_t)64 << 20));      // aliases logits
    ushort* Wb     = (ushort*)(ws + ((size_t)80 << 20));      // aliases logits

    cvt_kernel<<<dim3((NX4 + 3 * NW4) / 256), 256, 0, stream>>>(
        x, Wq, Wk, Wv, xb, Wb);

    qkv_kernel<<<dim3(MTOT / 128, DIM / 128, 3), 256, 0, stream>>>(
        xb, Wb, bq, bk, bv, q, kk, vt);
    qk_kernel<<<dim3(SEQ / 128, SEQ / 128, NB), 256, 0, stream>>>(q, kk, logits);
    softmax_kernel<<<NB * SEQ / 4, 256, 0, stream>>>(logits);
    pv_kernel<<<dim3(SEQ / 128, DIM / 128, NB), 256, 0, stream>>>(
        (const ushort*)logits, vt, out);
}